// Round 4
// baseline (223.887 us; speedup 1.0000x reference)
//
#include <hip/hip_runtime.h>
#include <hip/hip_bf16.h>

// DotAttention pooled: out[b,d] = sum_t c[b,t]*V[b,t,d],
//   c[b,t] = sum_q exp(s[q,t])/l_q (no-max softmax: s~N(0,1), exp safe),
//   s = (Q K^T)/16,  V == K == inputs.
//
// V5 path (needs 32 MB workspace):
//   conv_k     : inputs fp32 -> bf16, pre-swizzled tiles (unchanged).
//   attn_fused : per (b, 64-q block):
//     QK^T: 16x 32-row K tiles through a 3-buffer LDS ring (48 KB),
//           prefetch distance 2, counted s_waitcnt vmcnt(2) + raw
//           s_barrier, sched_barrier(0) pin, setprio around MFMAs.
//     softmax epilogue -> column weights accumulated into cfin via LDS
//           atomicAdd (kills the 8 KB cpart transpose buffer).
//     AV:   V rows read DIRECTLY from global (kbf slice L2-resident).
//     LDS/block 51.7 KB -> 3 blocks/CU (24 waves/CU vs round-3's 16):
//     cross-block phase overlap (QK-LDS || softmax-VALU || AV-L2) is the
//     round-3 bottleneck (70 us vs ~35 us overlapped floor).
// Fallback path (small ws): previous verified kernels.

typedef __bf16 bf16x8 __attribute__((ext_vector_type(8)));
typedef float  f32x4  __attribute__((ext_vector_type(4)));
typedef unsigned int u32;

#define B_    128
#define Tn    512
#define Dn    256
#define SCALE 0.0625f  // 1/sqrt(256)

#define WAITV2 asm volatile("s_waitcnt vmcnt(2)" ::: "memory")
#define WAITV0 asm volatile("s_waitcnt vmcnt(0)" ::: "memory")
#define BARRAW __builtin_amdgcn_s_barrier()
#define SCHED0 __builtin_amdgcn_sched_barrier(0)

// LDS index (bf16 units) for (row, 16B chunk); full xor swizzle — measured
// 0 bank conflicts. Valid for row in [0,32) tiles (row&31 == row).
__device__ __forceinline__ int lidx(int row, int ch) {
  return row * 256 + (((ch ^ (row & 31)) & 31) << 3);
}

__device__ __forceinline__ bf16x8 pack8(float4 v0, float4 v1) {
  bf16x8 w;
  w[0] = (__bf16)v0.x; w[1] = (__bf16)v0.y;
  w[2] = (__bf16)v0.z; w[3] = (__bf16)v0.w;
  w[4] = (__bf16)v1.x; w[5] = (__bf16)v1.y;
  w[6] = (__bf16)v1.z; w[7] = (__bf16)v1.w;
  return w;
}

// Direct global->LDS 16B copy (dest = wave-uniform base + lane*16).
__device__ __forceinline__ void gll16(const __bf16* g, __bf16* l) {
  __builtin_amdgcn_global_load_lds((const u32 __attribute__((address_space(1)))*)g,
                                   (u32 __attribute__((address_space(3)))*)l,
                                   16, 0, 0);
}

// ---------------- pre-pass: K fp32 -> bf16, tile-swizzled ----------------
// kbf[(b*8+tile64)*16384 + c*8] (c = row*32 + p) holds K[b][tile64*64+row]
// logical chunk ch = p ^ (row&31).  32-row tile t is the contiguous 16 KB
// slice at kbf + b*131072 + t*8192 (row&31 is tile-local for both halves).
__global__ void __launch_bounds__(512) conv_k(const float* __restrict__ inputs,
                                              __bf16* __restrict__ kbf) {
  const int tid = threadIdx.x;
  const int b = blockIdx.x & 127, tile = blockIdx.x >> 7;
#pragma unroll
  for (int i = 0; i < 4; ++i) {
    int c = i * 512 + tid;
    int row = c >> 5, p = c & 31;
    int ch = p ^ (row & 31);
    const float4* s =
        (const float4*)(inputs + ((size_t)b * Tn + tile * 64 + row) * Dn + ch * 8);
    *(bf16x8*)(kbf + (size_t)(b * 8 + tile) * 16384 + (size_t)c * 8) =
        pack8(s[0], s[1]);
  }
}

// ---------------- V5 fused QK^T + softmax + direct-AV kernel ----------------
__global__ void __launch_bounds__(512, 6) attn_fused(
    const __bf16* __restrict__ kbf, const float* __restrict__ query,
    float* __restrict__ out) {
  // Ring: 3 x 16 KB (32-row bf16 tiles) = 48 KB. Scratch (outside ring):
  //   lred 128 f32 | cfin 512 f32  -> 2.5 KB.  Total 51712 B -> 3 blocks/CU.
  __shared__ __bf16 smem[3 * 8192 + 1280];
  float* lred = (float*)(smem + 3 * 8192);  // [qg][th][16 q]
  float* cfin = lred + 128;                 // [512 t], atomic accum target

  const int tid  = threadIdx.x;
  const int bidx = blockIdx.x;
  const int b  = bidx & 127;  // same-b blocks 128 apart -> same XCD (L2)
  const int qt = bidx >> 7;   // 0..7 (64 q each)

  const int wave = tid >> 6, lane = tid & 63;
  const int quad = lane >> 4, l15 = lane & 15;
  const int qg = wave >> 1;  // 0..3: 16 q rows each
  const int th = wave & 1;   // 16-row half of each 32-row K tile

  const __bf16* ksrc = kbf + (size_t)b * 131072;  // 8192 bf16 per 32-row tile

  cfin[tid] = 0.f;  // atomic accum target; barriers below order vs use

  // Stage tile t (16 KB = 16 slices of 1 KB; wave w does slices 2w, 2w+1)
  // into ring buffer (t%3).
#define STAGE(t)                                                        \
  {                                                                     \
    _Pragma("unroll") for (int i_ = 0; i_ < 2; ++i_) {                  \
      int s_ = wave * 2 + i_;                                           \
      gll16(ksrc + (size_t)(t) * 8192 + s_ * 512 + lane * 8,            \
            smem + ((t) % 3) * 8192 + s_ * 512);                        \
    }                                                                   \
  }

  STAGE(0);

  // Q fragments resident in registers: 8 x bf16x8 = 32 VGPR per lane.
  const float* qsrc = query + ((size_t)b * 512 + qt * 64 + qg * 16 + l15) * Dn;
  bf16x8 a_[8];
#pragma unroll
  for (int dc = 0; dc < 8; ++dc) {
    const float4* p = (const float4*)(qsrc + dc * 32 + quad * 8);
    a_[dc] = pack8(p[0], p[1]);
  }

  STAGE(1);

  // acc[ti]: S[q = qt*64+qg*16+quad*4+r][t = ti*32 + th*16 + l15]
  f32x4 acc[16];
  f32x4 zero = {0.f, 0.f, 0.f, 0.f};
#pragma unroll
  for (int i = 0; i < 16; ++i) acc[i] = zero;

  // ---- QK^T loop: counted vmcnt + raw barrier (loads span barriers) ----
  // At iter tt wait: outstanding = tiles {tt, tt+1} (2 loads each; iter-0
  // also drains the a_ loads — one-time). vmcnt(2) retires tile tt;
  // barrier makes all waves' tile-tt writes visible; sched_barrier pins
  // the ds_reads below the barrier; then issue tt+2 over buffer (tt-1)%3
  // (all waves' reads of it completed before this barrier).
#pragma unroll
  for (int tt = 0; tt < 16; ++tt) {
    if (tt <= 14) { WAITV2; } else { WAITV0; }
    BARRAW;
    SCHED0;
    if (tt < 14) STAGE(tt + 2);
    const __bf16* cur = smem + (tt % 3) * 8192;
    __builtin_amdgcn_s_setprio(1);
#pragma unroll
    for (int dc = 0; dc < 8; ++dc) {
      bf16x8 bb = *(const bf16x8*)(cur + lidx(th * 16 + l15, dc * 4 + quad));
      acc[tt] = __builtin_amdgcn_mfma_f32_16x16x32_bf16(a_[dc], bb, acc[tt],
                                                        0, 0, 0);
    }
    __builtin_amdgcn_s_setprio(0);
  }

  // ---- softmax epilogue: exp, l_q, column weights c ----
  float rs[4] = {0.f, 0.f, 0.f, 0.f};
#pragma unroll
  for (int ti = 0; ti < 16; ++ti)
#pragma unroll
    for (int r = 0; r < 4; ++r) {
      float p = __expf(acc[ti][r] * SCALE);
      acc[ti][r] = p;
      rs[r] += p;
    }
#pragma unroll
  for (int off = 1; off <= 8; off <<= 1)
#pragma unroll
    for (int r = 0; r < 4; ++r) rs[r] += __shfl_xor(rs[r], off);

  if (l15 == 0) {
#pragma unroll
    for (int r = 0; r < 4; ++r)
      lred[(qg * 2 + th) * 16 + quad * 4 + r] = rs[r];
  }
  __syncthreads();

  float linv[4];
#pragma unroll
  for (int r = 0; r < 4; ++r) {
    int row = quad * 4 + r;
    linv[r] =
        1.f / (lred[(qg * 2 + 0) * 16 + row] + lred[(qg * 2 + 1) * 16 + row]);
  }

  // Column weights: 4 qg wave-pairs accumulate into cfin via LDS atomics
  // (replaces the 8 KB cpart transpose buffer + gather pass).
#pragma unroll
  for (int ti = 0; ti < 16; ++ti) {
    float v = 0.f;
#pragma unroll
    for (int r = 0; r < 4; ++r) v += acc[ti][r] * linv[r];
    v += __shfl_xor(v, 16);  // sum 4 quads (same t, different q rows)
    v += __shfl_xor(v, 32);
    if (quad == 0) atomicAdd(&cfin[ti * 32 + th * 16 + l15], v);
  }
  __syncthreads();

  // ---- AV pass: direct-global V reads (L2-resident kbf slice). ----
  // Thread owns d-chunk `dchunk` (8 floats); group tgrp handles rows
  // tgrp, tgrp+16, ... (32 rows). No LDS staging, no barriers.
  const int dchunk = tid & 31;
  const int tgrp   = tid >> 5;
  float o[8] = {0.f, 0.f, 0.f, 0.f, 0.f, 0.f, 0.f, 0.f};

#pragma unroll 8
  for (int i = 0; i < 32; ++i) {
    int row = tgrp + i * 16;
    int p = (dchunk ^ (row & 31)) & 31;
    const bf16x8* src = (const bf16x8*)(ksrc + (size_t)(row >> 6) * 16384 +
                                        ((row & 63) * 32 + p) * 8);
    bf16x8 v = *src;
    float c = cfin[row];  // lanes 0-31 same row -> LDS broadcast
#pragma unroll
    for (int j = 0; j < 8; ++j) o[j] += c * (float)v[j];
  }
  __syncthreads();  // ring reads long done; about to overlay ring with ored

  // Cross-tgrp reduce via LDS (ring region reused; stride 260 breaks banks).
  float* ored = (float*)smem;
  f32x4 o0 = {o[0], o[1], o[2], o[3]}, o1 = {o[4], o[5], o[6], o[7]};
  *(f32x4*)&ored[tgrp * 260 + dchunk * 8]     = o0;
  *(f32x4*)&ored[tgrp * 260 + dchunk * 8 + 4] = o1;
  __syncthreads();
  if (tid < 256) {
    float s = 0.f;
#pragma unroll
    for (int g = 0; g < 16; ++g) s += ored[g * 260 + tid];
    atomicAdd(out + (size_t)b * 256 + tid, s);
  }
#undef STAGE
}

// ---------------- fallback path (previous verified kernels) ----------------
__device__ __forceinline__ int lidx64(int row, int ch) {
  return row * 256 + (((ch ^ (row & 31)) & 31) << 3);
}

__device__ __forceinline__ void kload(const float* __restrict__ src, int tid,
                                      float4* pre) {
#pragma unroll
  for (int i = 0; i < 4; ++i) {
    int u = i * 512 + tid;
    int row = u >> 5, ch = u & 31;
    const float4* p = (const float4*)(src + row * 256 + ch * 8);
    pre[2 * i]     = p[0];
    pre[2 * i + 1] = p[1];
  }
}

__device__ __forceinline__ void kstore(__bf16* dst, int tid,
                                       const float4* pre) {
#pragma unroll
  for (int i = 0; i < 4; ++i) {
    int u = i * 512 + tid;
    int row = u >> 5, ch = u & 31;
    *(bf16x8*)(dst + lidx64(row, ch)) = pack8(pre[2 * i], pre[2 * i + 1]);
  }
}

__global__ void __launch_bounds__(512, 2) attn_qk(
    const float* __restrict__ inputs, const float* __restrict__ query,
    float* __restrict__ c_ws) {
  __shared__ __bf16 smem[128 * 256 + 2 * 64 * 256];
  __bf16* Qs = smem;
  __bf16* Kb[2] = {smem + 128 * 256, smem + 128 * 256 + 64 * 256};

  const int tid  = threadIdx.x;
  const int bidx = blockIdx.x;
  const int b  = bidx & 127;
  const int qt = bidx >> 7;

  const float* qsrc = query  + ((size_t)b * 512 + (size_t)qt * 128) * Dn;
  const float* ksrc = inputs + (size_t)b * Tn * Dn;

  const int wave = tid >> 6, lane = tid & 63;
  const int quad = lane >> 4, l15 = lane & 15;
  const int qg = wave >> 1;
  const int th = wave & 1;

  float4 pre[2][8];
  kload(ksrc, tid, pre[0]);

#pragma unroll
  for (int i = 0; i < 8; ++i) {
    int u = i * 512 + tid;
    int row = u >> 5, ch = u & 31;
    const float4* p = (const float4*)(qsrc + row * 256 + ch * 8);
    *(bf16x8*)(Qs + lidx64(row, ch)) = pack8(p[0], p[1]);
  }

  kload(ksrc + (size_t)1 * 64 * Dn, tid, pre[1]);
  __syncthreads();

  kstore(Kb[0], tid, pre[0]);
  kload(ksrc + (size_t)2 * 64 * Dn, tid, pre[0]);
  __syncthreads();

  f32x4 acc[8][2][2];
  f32x4 zero = {0.f, 0.f, 0.f, 0.f};
#pragma unroll
  for (int tt = 0; tt < 8; ++tt)
#pragma unroll
    for (int ct = 0; ct < 2; ++ct) {
      acc[tt][ct][0] = zero;
      acc[tt][ct][1] = zero;
    }

#pragma unroll
  for (int tt = 0; tt < 8; ++tt) {
    if (tt < 7) kstore(Kb[(tt + 1) & 1], tid, pre[(tt + 1) & 1]);
    if (tt < 5) kload(ksrc + (size_t)(tt + 3) * 64 * Dn, tid, pre[(tt + 1) & 1]);

    const __bf16* cur = Kb[tt & 1];
#pragma unroll
    for (int dc = 0; dc < 8; ++dc) {
      bf16x8 a0 = *(const bf16x8*)(Qs + lidx64(qg * 32 + l15, dc * 4 + quad));
      bf16x8 a1 = *(const bf16x8*)(Qs + lidx64(qg * 32 + 16 + l15, dc * 4 + quad));
#pragma unroll
      for (int ct = 0; ct < 2; ++ct) {
        bf16x8 bb =
            *(const bf16x8*)(cur + lidx64(th * 32 + ct * 16 + l15, dc * 4 + quad));
        acc[tt][ct][0] = __builtin_amdgcn_mfma_f32_16x16x32_bf16(
            a0, bb, acc[tt][ct][0], 0, 0, 0);
        acc[tt][ct][1] = __builtin_amdgcn_mfma_f32_16x16x32_bf16(
            a1, bb, acc[tt][ct][1], 0, 0, 0);
      }
    }
    __syncthreads();
  }

  float* lred  = (float*)Kb[0];
  float* cpart = (float*)Kb[0] + 256;

  float rs[2][4];
#pragma unroll
  for (int m = 0; m < 2; ++m)
#pragma unroll
    for (int r = 0; r < 4; ++r) rs[m][r] = 0.f;
#pragma unroll
  for (int tt = 0; tt < 8; ++tt)
#pragma unroll
    for (int ct = 0; ct < 2; ++ct)
#pragma unroll
      for (int m = 0; m < 2; ++m)
#pragma unroll
        for (int r = 0; r < 4; ++r) {
          float p = __expf(acc[tt][ct][m][r] * SCALE);
          acc[tt][ct][m][r] = p;
          rs[m][r] += p;
        }
#pragma unroll
  for (int off = 1; off <= 8; off <<= 1)
#pragma unroll
    for (int m = 0; m < 2; ++m)
#pragma unroll
      for (int r = 0; r < 4; ++r) rs[m][r] += __shfl_xor(rs[m][r], off);

  if (l15 == 0) {
#pragma unroll
    for (int m = 0; m < 2; ++m)
#pragma unroll
      for (int r = 0; r < 4; ++r)
        lred[(qg * 2 + th) * 32 + m * 16 + quad * 4 + r] = rs[m][r];
  }
  __syncthreads();

  float linv[2][4];
#pragma unroll
  for (int m = 0; m < 2; ++m)
#pragma unroll
    for (int r = 0; r < 4; ++r) {
      int row = m * 16 + quad * 4 + r;
      linv[m][r] =
          1.f / (lred[(qg * 2 + 0) * 32 + row] + lred[(qg * 2 + 1) * 32 + row]);
    }

#pragma unroll
  for (int tt = 0; tt < 8; ++tt)
#pragma unroll
    for (int ct = 0; ct < 2; ++ct) {
      float v = 0.f;
#pragma unroll
      for (int m = 0; m < 2; ++m)
#pragma unroll
        for (int r = 0; r < 4; ++r) v += acc[tt][ct][m][r] * linv[m][r];
      v += __shfl_xor(v, 16);
      v += __shfl_xor(v, 32);
      if (quad == 0)
        cpart[qg * 512 + tt * 64 + th * 32 + ct * 16 + l15] = v;
    }
  __syncthreads();

  float* cout = c_ws + ((size_t)qt * B_ + b) * Tn;
#pragma unroll
  for (int t = tid; t < 512; t += 256) {
    if (t < 512)
      cout[t] = cpart[t] + cpart[512 + t] + cpart[1024 + t] + cpart[1536 + t];
  }
}

template <int NSL>
__global__ void __launch_bounds__(256) attn_av(
    const float* __restrict__ inputs, const float* __restrict__ c_ws,
    float* __restrict__ out) {
  __shared__ float cs[64];
  __shared__ float psum[3][256];
  const int bid = blockIdx.x, tid = threadIdx.x;
  const int b = bid & 127, sl = bid >> 7;

  if (tid < 64) {
    int t = sl * 64 + tid;
    float s = 0.f;
#pragma unroll
    for (int i = 0; i < NSL; ++i) s += c_ws[(size_t)(i * B_ + b) * Tn + t];
    cs[tid] = s;
  }
  __syncthreads();

  const int w = tid >> 6, d4 = tid & 63;
  const float4* vb =
      (const float4*)(inputs + ((size_t)b * Tn + sl * 64 + w * 16) * Dn) + d4;
  float ox = 0.f, oy = 0.f, oz = 0.f, ow = 0.f;
#pragma unroll
  for (int j = 0; j < 16; ++j) {
    float c = cs[w * 16 + j];
    float4 v = vb[(size_t)j * 64];
    ox += c * v.x; oy += c * v.y; oz += c * v.z; ow += c * v.w;
  }
  if (w) {
    float4 t = {ox, oy, oz, ow};
    *(float4*)&psum[w - 1][d4 * 4] = t;
  }
  __syncthreads();
  if (!w) {
    float4 p0 = *(float4*)&psum[0][d4 * 4];
    float4 p1 = *(float4*)&psum[1][d4 * 4];
    float4 p2 = *(float4*)&psum[2][d4 * 4];
    float* op = out + b * 256 + d4 * 4;
    atomicAdd(op + 0, ox + p0.x + p1.x + p2.x);
    atomicAdd(op + 1, oy + p0.y + p1.y + p2.y);
    atomicAdd(op + 2, oz + p0.z + p1.z + p2.z);
    atomicAdd(op + 3, ow + p0.w + p1.w + p2.w);
  }
}

extern "C" void kernel_launch(void* const* d_in, const int* in_sizes, int n_in,
                              void* d_out, int out_size, void* d_ws, size_t ws_size,
                              hipStream_t stream) {
  const float* inputs = (const float*)d_in[0];  // [B,T,D]
  const float* query  = (const float*)d_in[1];  // [B,Q,D]
  float* out  = (float*)d_out;                  // [B,D]

  hipMemsetAsync(out, 0, (size_t)B_ * Dn * sizeof(float), stream);

  const size_t kbytes = (size_t)B_ * Tn * Dn * sizeof(__bf16);  // 32 MB
  if (ws_size >= kbytes) {
    __bf16* kbf = (__bf16*)d_ws;
    conv_k    <<<dim3(1024), dim3(512), 0, stream>>>(inputs, kbf);
    attn_fused<<<dim3(1024), dim3(512), 0, stream>>>(kbf, query, out);
  } else {
    float* c_ws = (float*)d_ws;                 // 1 MB
    attn_qk<<<dim3(512), dim3(512), 0, stream>>>(inputs, query, c_ws);
    attn_av<4><<<dim3(1024), dim3(256), 0, stream>>>(inputs, c_ws, out);
  }
}

// Round 5
// 200.995 us; speedup vs baseline: 1.1139x; 1.1139x over previous
//
#include <hip/hip_runtime.h>
#include <hip/hip_bf16.h>
#include <hip/hip_cooperative_groups.h>

namespace cg = cooperative_groups;

// DotAttention pooled: out[b,d] = sum_t c[b,t]*V[b,t,d],
//   c[b,t] = sum_q exp(s[q,t])/l_q (no-max softmax: s~N(0,1), exp safe),
//   s = (Q K^T)/16,  V == K == inputs.
//
// V6: single cooperative kernel (512 blocks = b x q-half, 2/CU):
//   phase0: each block converts its 128 KB K-share fp32->bf16 into ws
//           (tile-swizzled), grid.sync() — kills the standalone conv_k
//           kernel + its launch gap.
//   phase1: 4 q-chunks of 64 q: QK^T over 16x 32-row K tiles via 3-buffer
//           LDS ring, counted s_waitcnt vmcnt(2) + raw s_barrier
//           (loads in flight across barriers), setprio on MFMAs.
//           acc = 64 VGPR reused across chunks; per-chunk softmax ->
//           cfin via LDS atomicAdd.
//   phase2: AV with V rows direct from global (L2-resident slice),
//           atomicAdd partials to out.
// REG DISCIPLINE: __launch_bounds__(512,4) = 128-reg cap. (512,6) in R4
// capped at 85 -> 76.8 MB scratch spill, 70->104 us. Never again.
// Fallbacks: no-coop -> conv_k + attn_fused(512,4); small ws -> legacy.

typedef __bf16 bf16x8 __attribute__((ext_vector_type(8)));
typedef float  f32x4  __attribute__((ext_vector_type(4)));
typedef unsigned int u32;

#define B_    128
#define Tn    512
#define Dn    256
#define SCALE 0.0625f  // 1/sqrt(256)

#define WAITV2 asm volatile("s_waitcnt vmcnt(2)" ::: "memory")
#define WAITV0 asm volatile("s_waitcnt vmcnt(0)" ::: "memory")
#define BARRAW __builtin_amdgcn_s_barrier()
#define SCHED0 __builtin_amdgcn_sched_barrier(0)

// LDS index (bf16 units) for (row, 16B chunk); full xor swizzle — measured
// 0 bank conflicts. Valid for row in [0,32) tiles (row&31 == row).
__device__ __forceinline__ int lidx(int row, int ch) {
  return row * 256 + (((ch ^ (row & 31)) & 31) << 3);
}

__device__ __forceinline__ bf16x8 pack8(float4 v0, float4 v1) {
  bf16x8 w;
  w[0] = (__bf16)v0.x; w[1] = (__bf16)v0.y;
  w[2] = (__bf16)v0.z; w[3] = (__bf16)v0.w;
  w[4] = (__bf16)v1.x; w[5] = (__bf16)v1.y;
  w[6] = (__bf16)v1.z; w[7] = (__bf16)v1.w;
  return w;
}

// Direct global->LDS 16B copy (dest = wave-uniform base + lane*16).
__device__ __forceinline__ void gll16(const __bf16* g, __bf16* l) {
  __builtin_amdgcn_global_load_lds((const u32 __attribute__((address_space(1)))*)g,
                                   (u32 __attribute__((address_space(3)))*)l,
                                   16, 0, 0);
}

// kbf layout: [(b*8+tile64)*16384 + c*8], c = row*32 + p, chunk ch = p^(row&31)
// pre-applied so gll16 (linear dest) + lidx (swizzled read) pair up.
// 32-row ring tile t = contiguous 16 KB at kbf + b*131072 + t*8192.

// ---------------- V6 cooperative all-in-one kernel ----------------
__global__ void __launch_bounds__(512, 4) attn_coop(
    const float* __restrict__ inputs, const float* __restrict__ query,
    __bf16* __restrict__ kbf, float* __restrict__ out) {
  // Ring: 3 x 16 KB = 48 KB. Scratch: lred 128 f32 | cfin 512 f32.
  __shared__ __bf16 smem[3 * 8192 + 1280];  // 51712 B
  float* lred = (float*)(smem + 3 * 8192);  // [qg][th][16 q]
  float* cfin = lred + 128;                 // [512 t], atomic accum

  const int tid = threadIdx.x;
  const int b = blockIdx.x & 127;  // same-b pair 128 apart -> same XCD slot
  const int h = blockIdx.x >> 7;   // q-half: rows [h*256, h*256+256)

  // ---- phase 0: convert K-share fp32 -> bf16 (tile64s [4h, 4h+4)) ----
#pragma unroll 4
  for (int i = 0; i < 16; ++i) {
    int u = i * 512 + tid;            // 0..8191 chunks of 16B
    int T = 4 * h + (u >> 11);        // 4 tile64s, 2048 chunks each
    int c = u & 2047;
    int row = c >> 5, p = c & 31;
    int ch = p ^ (row & 31);
    const float4* s =
        (const float4*)(inputs + ((size_t)b * Tn + T * 64 + row) * Dn + ch * 8);
    *(bf16x8*)(kbf + (size_t)(b * 8 + T) * 16384 + (size_t)c * 8) =
        pack8(s[0], s[1]);
  }
  cfin[tid] = 0.f;
  cg::this_grid().sync();  // sibling block's K-share now visible

  const int wave = tid >> 6, lane = tid & 63;
  const int quad = lane >> 4, l15 = lane & 15;
  const int qg = wave >> 1;  // 0..3: 16 q rows each
  const int th = wave & 1;   // 16-row half of each 32-row tile

  const __bf16* ksrc = kbf + (size_t)b * 131072;

#define STAGE(t)                                                        \
  {                                                                     \
    _Pragma("unroll") for (int i_ = 0; i_ < 2; ++i_) {                  \
      int s_ = wave * 2 + i_;                                           \
      gll16(ksrc + (size_t)(t) * 8192 + s_ * 512 + lane * 8,            \
            smem + ((t) % 3) * 8192 + s_ * 512);                        \
    }                                                                   \
  }

  // ---- phase 1: 4 q-chunks of 64 q; acc regs reused each chunk ----
#pragma unroll 1
  for (int qc = 0; qc < 4; ++qc) {
    STAGE(0);

    const float* qsrc =
        query + ((size_t)b * 512 + h * 256 + qc * 64 + qg * 16 + l15) * Dn;
    bf16x8 a_[8];  // 32 VGPR
#pragma unroll
    for (int dc = 0; dc < 8; ++dc) {
      const float4* p = (const float4*)(qsrc + dc * 32 + quad * 8);
      a_[dc] = pack8(p[0], p[1]);
    }

    STAGE(1);

    // acc[ti]: S[q = ...+qg*16+quad*4+r][t = ti*32 + th*16 + l15]
    f32x4 acc[16];
    f32x4 zero = {0.f, 0.f, 0.f, 0.f};
#pragma unroll
    for (int i = 0; i < 16; ++i) acc[i] = zero;

    // Counted vmcnt + raw barrier: at iter tt, outstanding = tiles
    // {tt, tt+1} (2 loads each; qc-iter0 also drains a_ — one-time).
    // vmcnt(2) retires tile tt; barrier publishes all waves' writes;
    // then overwrite buffer (tt-1)%3 with tile tt+2 (reads of it were
    // completed by every wave before the previous barrier).
#pragma unroll
    for (int tt = 0; tt < 16; ++tt) {
      if (tt <= 14) { WAITV2; } else { WAITV0; }
      BARRAW;
      SCHED0;
      if (tt < 14) STAGE(tt + 2);
      const __bf16* cur = smem + (tt % 3) * 8192;
      __builtin_amdgcn_s_setprio(1);
#pragma unroll
      for (int dc = 0; dc < 8; ++dc) {
        bf16x8 bb = *(const bf16x8*)(cur + lidx(th * 16 + l15, dc * 4 + quad));
        acc[tt] = __builtin_amdgcn_mfma_f32_16x16x32_bf16(a_[dc], bb, acc[tt],
                                                          0, 0, 0);
      }
      __builtin_amdgcn_s_setprio(0);
    }

    // softmax epilogue: exp, row-sum l_q, column weights into cfin
    float rs[4] = {0.f, 0.f, 0.f, 0.f};
#pragma unroll
    for (int ti = 0; ti < 16; ++ti)
#pragma unroll
      for (int r = 0; r < 4; ++r) {
        float p = __expf(acc[ti][r] * SCALE);
        acc[ti][r] = p;
        rs[r] += p;
      }
#pragma unroll
    for (int off = 1; off <= 8; off <<= 1)
#pragma unroll
      for (int r = 0; r < 4; ++r) rs[r] += __shfl_xor(rs[r], off);

    if (l15 == 0) {
#pragma unroll
      for (int r = 0; r < 4; ++r)
        lred[(qg * 2 + th) * 16 + quad * 4 + r] = rs[r];
    }
    // This barrier also orders: all waves' buf-0 ds_reads (tt=15) complete
    // before next chunk's STAGE(0) overwrites it.
    __syncthreads();

    float linv[4];
#pragma unroll
    for (int r = 0; r < 4; ++r) {
      int row = quad * 4 + r;
      linv[r] = 1.f / (lred[(qg * 2 + 0) * 16 + row] +
                       lred[(qg * 2 + 1) * 16 + row]);
    }

#pragma unroll
    for (int ti = 0; ti < 16; ++ti) {
      float v = 0.f;
#pragma unroll
      for (int r = 0; r < 4; ++r) v += acc[ti][r] * linv[r];
      v += __shfl_xor(v, 16);  // sum 4 quads (same t, different q rows)
      v += __shfl_xor(v, 32);
      if (quad == 0) atomicAdd(&cfin[ti * 32 + th * 16 + l15], v);
    }
  }
  __syncthreads();  // all cfin contributions visible

  // ---- phase 2: AV, V rows direct from global (L2-resident slice) ----
  const int dchunk = tid & 31;
  const int tgrp   = tid >> 5;
  float o[8] = {0.f, 0.f, 0.f, 0.f, 0.f, 0.f, 0.f, 0.f};

#pragma unroll 8
  for (int i = 0; i < 32; ++i) {
    int row = tgrp + i * 16;
    int p = (dchunk ^ (row & 31)) & 31;
    const bf16x8* src = (const bf16x8*)(ksrc + (size_t)(row >> 6) * 16384 +
                                        ((row & 63) * 32 + p) * 8);
    bf16x8 v = *src;
    float c = cfin[row];  // lanes 0-31 same row -> LDS broadcast
#pragma unroll
    for (int j = 0; j < 8; ++j) o[j] += c * (float)v[j];
  }
  __syncthreads();  // about to overlay ring with ored

  float* ored = (float*)smem;
  f32x4 o0 = {o[0], o[1], o[2], o[3]}, o1 = {o[4], o[5], o[6], o[7]};
  *(f32x4*)&ored[tgrp * 260 + dchunk * 8]     = o0;
  *(f32x4*)&ored[tgrp * 260 + dchunk * 8 + 4] = o1;
  __syncthreads();
  if (tid < 256) {
    float s = 0.f;
#pragma unroll
    for (int g = 0; g < 16; ++g) s += ored[g * 260 + tid];
    atomicAdd(out + (size_t)b * 256 + tid, s);
  }
#undef STAGE
}

// ---------------- non-coop fallback: conv_k + attn_fused(512,4) ----------------
__global__ void __launch_bounds__(512) conv_k(const float* __restrict__ inputs,
                                              __bf16* __restrict__ kbf) {
  const int tid = threadIdx.x;
  const int b = blockIdx.x & 127, tile = blockIdx.x >> 7;
#pragma unroll
  for (int i = 0; i < 4; ++i) {
    int c = i * 512 + tid;
    int row = c >> 5, p = c & 31;
    int ch = p ^ (row & 31);
    const float4* s =
        (const float4*)(inputs + ((size_t)b * Tn + tile * 64 + row) * Dn + ch * 8);
    *(bf16x8*)(kbf + (size_t)(b * 8 + tile) * 16384 + (size_t)c * 8) =
        pack8(s[0], s[1]);
  }
}

__global__ void __launch_bounds__(512, 4) attn_fused(
    const __bf16* __restrict__ kbf, const float* __restrict__ query,
    float* __restrict__ out) {
  __shared__ __bf16 smem[3 * 8192 + 1280];
  float* lred = (float*)(smem + 3 * 8192);
  float* cfin = lred + 128;

  const int tid  = threadIdx.x;
  const int b  = blockIdx.x & 127;
  const int qt = blockIdx.x >> 7;

  const int wave = tid >> 6, lane = tid & 63;
  const int quad = lane >> 4, l15 = lane & 15;
  const int qg = wave >> 1;
  const int th = wave & 1;

  const __bf16* ksrc = kbf + (size_t)b * 131072;
  cfin[tid] = 0.f;

#define STAGE(t)                                                        \
  {                                                                     \
    _Pragma("unroll") for (int i_ = 0; i_ < 2; ++i_) {                  \
      int s_ = wave * 2 + i_;                                           \
      gll16(ksrc + (size_t)(t) * 8192 + s_ * 512 + lane * 8,            \
            smem + ((t) % 3) * 8192 + s_ * 512);                        \
    }                                                                   \
  }

  STAGE(0);
  const float* qsrc = query + ((size_t)b * 512 + qt * 64 + qg * 16 + l15) * Dn;
  bf16x8 a_[8];
#pragma unroll
  for (int dc = 0; dc < 8; ++dc) {
    const float4* p = (const float4*)(qsrc + dc * 32 + quad * 8);
    a_[dc] = pack8(p[0], p[1]);
  }
  STAGE(1);

  f32x4 acc[16];
  f32x4 zero = {0.f, 0.f, 0.f, 0.f};
#pragma unroll
  for (int i = 0; i < 16; ++i) acc[i] = zero;

#pragma unroll
  for (int tt = 0; tt < 16; ++tt) {
    if (tt <= 14) { WAITV2; } else { WAITV0; }
    BARRAW;
    SCHED0;
    if (tt < 14) STAGE(tt + 2);
    const __bf16* cur = smem + (tt % 3) * 8192;
    __builtin_amdgcn_s_setprio(1);
#pragma unroll
    for (int dc = 0; dc < 8; ++dc) {
      bf16x8 bb = *(const bf16x8*)(cur + lidx(th * 16 + l15, dc * 4 + quad));
      acc[tt] = __builtin_amdgcn_mfma_f32_16x16x32_bf16(a_[dc], bb, acc[tt],
                                                        0, 0, 0);
    }
    __builtin_amdgcn_s_setprio(0);
  }

  float rs[4] = {0.f, 0.f, 0.f, 0.f};
#pragma unroll
  for (int ti = 0; ti < 16; ++ti)
#pragma unroll
    for (int r = 0; r < 4; ++r) {
      float p = __expf(acc[ti][r] * SCALE);
      acc[ti][r] = p;
      rs[r] += p;
    }
#pragma unroll
  for (int off = 1; off <= 8; off <<= 1)
#pragma unroll
    for (int r = 0; r < 4; ++r) rs[r] += __shfl_xor(rs[r], off);

  if (l15 == 0) {
#pragma unroll
    for (int r = 0; r < 4; ++r)
      lred[(qg * 2 + th) * 16 + quad * 4 + r] = rs[r];
  }
  __syncthreads();

  float linv[4];
#pragma unroll
  for (int r = 0; r < 4; ++r) {
    int row = quad * 4 + r;
    linv[r] =
        1.f / (lred[(qg * 2 + 0) * 16 + row] + lred[(qg * 2 + 1) * 16 + row]);
  }

#pragma unroll
  for (int ti = 0; ti < 16; ++ti) {
    float v = 0.f;
#pragma unroll
    for (int r = 0; r < 4; ++r) v += acc[ti][r] * linv[r];
    v += __shfl_xor(v, 16);
    v += __shfl_xor(v, 32);
    if (quad == 0) atomicAdd(&cfin[ti * 32 + th * 16 + l15], v);
  }
  __syncthreads();

  const int dchunk = tid & 31;
  const int tgrp   = tid >> 5;
  float o[8] = {0.f, 0.f, 0.f, 0.f, 0.f, 0.f, 0.f, 0.f};

#pragma unroll 8
  for (int i = 0; i < 32; ++i) {
    int row = tgrp + i * 16;
    int p = (dchunk ^ (row & 31)) & 31;
    const bf16x8* src = (const bf16x8*)(ksrc + (size_t)(row >> 6) * 16384 +
                                        ((row & 63) * 32 + p) * 8);
    bf16x8 v = *src;
    float c = cfin[row];
#pragma unroll
    for (int j = 0; j < 8; ++j) o[j] += c * (float)v[j];
  }
  __syncthreads();

  float* ored = (float*)smem;
  f32x4 o0 = {o[0], o[1], o[2], o[3]}, o1 = {o[4], o[5], o[6], o[7]};
  *(f32x4*)&ored[tgrp * 260 + dchunk * 8]     = o0;
  *(f32x4*)&ored[tgrp * 260 + dchunk * 8 + 4] = o1;
  __syncthreads();
  if (tid < 256) {
    float s = 0.f;
#pragma unroll
    for (int g = 0; g < 16; ++g) s += ored[g * 260 + tid];
    atomicAdd(out + (size_t)b * 256 + tid, s);
  }
#undef STAGE
}

// ---------------- legacy small-ws fallback ----------------
__device__ __forceinline__ void kload(const float* __restrict__ src, int tid,
                                      float4* pre) {
#pragma unroll
  for (int i = 0; i < 4; ++i) {
    int u = i * 512 + tid;
    int row = u >> 5, ch = u & 31;
    const float4* p = (const float4*)(src + row * 256 + ch * 8);
    pre[2 * i]     = p[0];
    pre[2 * i + 1] = p[1];
  }
}

__device__ __forceinline__ void kstore(__bf16* dst, int tid,
                                       const float4* pre) {
#pragma unroll
  for (int i = 0; i < 4; ++i) {
    int u = i * 512 + tid;
    int row = u >> 5, ch = u & 31;
    *(bf16x8*)(dst + lidx(row, ch)) = pack8(pre[2 * i], pre[2 * i + 1]);
  }
}

__global__ void __launch_bounds__(512, 2) attn_qk(
    const float* __restrict__ inputs, const float* __restrict__ query,
    float* __restrict__ c_ws) {
  __shared__ __bf16 smem[128 * 256 + 2 * 64 * 256];
  __bf16* Qs = smem;
  __bf16* Kb[2] = {smem + 128 * 256, smem + 128 * 256 + 64 * 256};

  const int tid  = threadIdx.x;
  const int b  = blockIdx.x & 127;
  const int qt = blockIdx.x >> 7;

  const float* qsrc = query  + ((size_t)b * 512 + (size_t)qt * 128) * Dn;
  const float* ksrc = inputs + (size_t)b * Tn * Dn;

  const int wave = tid >> 6, lane = tid & 63;
  const int quad = lane >> 4, l15 = lane & 15;
  const int qg = wave >> 1;
  const int th = wave & 1;

  float4 pre[2][8];
  kload(ksrc, tid, pre[0]);

#pragma unroll
  for (int i = 0; i < 8; ++i) {
    int u = i * 512 + tid;
    int row = u >> 5, ch = u & 31;
    const float4* p = (const float4*)(qsrc + row * 256 + ch * 8);
    *(bf16x8*)(Qs + lidx(row, ch)) = pack8(p[0], p[1]);
  }

  kload(ksrc + (size_t)1 * 64 * Dn, tid, pre[1]);
  __syncthreads();

  kstore(Kb[0], tid, pre[0]);
  kload(ksrc + (size_t)2 * 64 * Dn, tid, pre[0]);
  __syncthreads();

  f32x4 acc[8][2][2];
  f32x4 zero = {0.f, 0.f, 0.f, 0.f};
#pragma unroll
  for (int tt = 0; tt < 8; ++tt)
#pragma unroll
    for (int ct = 0; ct < 2; ++ct) {
      acc[tt][ct][0] = zero;
      acc[tt][ct][1] = zero;
    }

#pragma unroll
  for (int tt = 0; tt < 8; ++tt) {
    if (tt < 7) kstore(Kb[(tt + 1) & 1], tid, pre[(tt + 1) & 1]);
    if (tt < 5) kload(ksrc + (size_t)(tt + 3) * 64 * Dn, tid, pre[(tt + 1) & 1]);

    const __bf16* cur = Kb[tt & 1];
#pragma unroll
    for (int dc = 0; dc < 8; ++dc) {
      bf16x8 a0 = *(const bf16x8*)(Qs + lidx(qg * 32 + l15, dc * 4 + quad));
      bf16x8 a1 = *(const bf16x8*)(Qs + lidx(qg * 32 + 16 + l15, dc * 4 + quad));
#pragma unroll
      for (int ct = 0; ct < 2; ++ct) {
        bf16x8 bb =
            *(const bf16x8*)(cur + lidx(th * 32 + ct * 16 + l15, dc * 4 + quad));
        acc[tt][ct][0] = __builtin_amdgcn_mfma_f32_16x16x32_bf16(
            a0, bb, acc[tt][ct][0], 0, 0, 0);
        acc[tt][ct][1] = __builtin_amdgcn_mfma_f32_16x16x32_bf16(
            a1, bb, acc[tt][ct][1], 0, 0, 0);
      }
    }
    __syncthreads();
  }

  float* lred  = (float*)Kb[0];
  float* cpart = (float*)Kb[0] + 256;

  float rs[2][4];
#pragma unroll
  for (int m = 0; m < 2; ++m)
#pragma unroll
    for (int r = 0; r < 4; ++r) rs[m][r] = 0.f;
#pragma unroll
  for (int tt = 0; tt < 8; ++tt)
#pragma unroll
    for (int ct = 0; ct < 2; ++ct)
#pragma unroll
      for (int m = 0; m < 2; ++m)
#pragma unroll
        for (int r = 0; r < 4; ++r) {
          float p = __expf(acc[tt][ct][m][r] * SCALE);
          acc[tt][ct][m][r] = p;
          rs[m][r] += p;
        }
#pragma unroll
  for (int off = 1; off <= 8; off <<= 1)
#pragma unroll
    for (int m = 0; m < 2; ++m)
#pragma unroll
      for (int r = 0; r < 4; ++r) rs[m][r] += __shfl_xor(rs[m][r], off);

  if (l15 == 0) {
#pragma unroll
    for (int m = 0; m < 2; ++m)
#pragma unroll
      for (int r = 0; r < 4; ++r)
        lred[(qg * 2 + th) * 32 + m * 16 + quad * 4 + r] = rs[m][r];
  }
  __syncthreads();

  float linv[2][4];
#pragma unroll
  for (int m = 0; m < 2; ++m)
#pragma unroll
    for (int r = 0; r < 4; ++r) {
      int row = m * 16 + quad * 4 + r;
      linv[m][r] =
          1.f / (lred[(qg * 2 + 0) * 32 + row] + lred[(qg * 2 + 1) * 32 + row]);
    }

#pragma unroll
  for (int tt = 0; tt < 8; ++tt)
#pragma unroll
    for (int ct = 0; ct < 2; ++ct) {
      float v = 0.f;
#pragma unroll
      for (int m = 0; m < 2; ++m)
#pragma unroll
        for (int r = 0; r < 4; ++r) v += acc[tt][ct][m][r] * linv[m][r];
      v += __shfl_xor(v, 16);
      v += __shfl_xor(v, 32);
      if (quad == 0)
        cpart[qg * 512 + tt * 64 + th * 32 + ct * 16 + l15] = v;
    }
  __syncthreads();

  float* cout = c_ws + ((size_t)qt * B_ + b) * Tn;
#pragma unroll
  for (int t = tid; t < 512; t += 256) {
    if (t < 512)
      cout[t] = cpart[t] + cpart[512 + t] + cpart[1024 + t] + cpart[1536 + t];
  }
}

template <int NSL>
__global__ void __launch_bounds__(256) attn_av(
    const float* __restrict__ inputs, const float* __restrict__ c_ws,
    float* __restrict__ out) {
  __shared__ float cs[64];
  __shared__ float psum[3][256];
  const int bid = blockIdx.x, tid = threadIdx.x;
  const int b = bid & 127, sl = bid >> 7;

  if (tid < 64) {
    int t = sl * 64 + tid;
    float s = 0.f;
#pragma unroll
    for (int i = 0; i < NSL; ++i) s += c_ws[(size_t)(i * B_ + b) * Tn + t];
    cs[tid] = s;
  }
  __syncthreads();

  const int w = tid >> 6, d4 = tid & 63;
  const float4* vb =
      (const float4*)(inputs + ((size_t)b * Tn + sl * 64 + w * 16) * Dn) + d4;
  float ox = 0.f, oy = 0.f, oz = 0.f, ow = 0.f;
#pragma unroll
  for (int j = 0; j < 16; ++j) {
    float c = cs[w * 16 + j];
    float4 v = vb[(size_t)j * 64];
    ox += c * v.x; oy += c * v.y; oz += c * v.z; ow += c * v.w;
  }
  if (w) {
    float4 t = {ox, oy, oz, ow};
    *(float4*)&psum[w - 1][d4 * 4] = t;
  }
  __syncthreads();
  if (!w) {
    float4 p0 = *(float4*)&psum[0][d4 * 4];
    float4 p1 = *(float4*)&psum[1][d4 * 4];
    float4 p2 = *(float4*)&psum[2][d4 * 4];
    float* op = out + b * 256 + d4 * 4;
    atomicAdd(op + 0, ox + p0.x + p1.x + p2.x);
    atomicAdd(op + 1, oy + p0.y + p1.y + p2.y);
    atomicAdd(op + 2, oz + p0.z + p1.z + p2.z);
    atomicAdd(op + 3, ow + p0.w + p1.w + p2.w);
  }
}

extern "C" void kernel_launch(void* const* d_in, const int* in_sizes, int n_in,
                              void* d_out, int out_size, void* d_ws, size_t ws_size,
                              hipStream_t stream) {
  const float* inputs = (const float*)d_in[0];  // [B,T,D]
  const float* query  = (const float*)d_in[1];  // [B,Q,D]
  float* out  = (float*)d_out;                  // [B,D]

  hipMemsetAsync(out, 0, (size_t)B_ * Dn * sizeof(float), stream);

  const size_t kbytes = (size_t)B_ * Tn * Dn * sizeof(__bf16);  // 32 MB
  if (ws_size >= kbytes) {
    __bf16* kbf = (__bf16*)d_ws;

    // One-time host-side gate: cooperative support + 512-block co-residency.
    static int coop_ok = -1;
    if (coop_ok < 0) {
      int dev = 0;
      (void)hipGetDevice(&dev);
      int attr = 0;
      (void)hipDeviceGetAttribute(&attr, hipDeviceAttributeCooperativeLaunch, dev);
      int ncu = 0;
      (void)hipDeviceGetAttribute(&ncu, hipDeviceAttributeMultiprocessorCount, dev);
      int nb = 0;
      hipError_t oe =
          hipOccupancyMaxActiveBlocksPerMultiprocessor(&nb, attn_coop, 512, 0);
      coop_ok = (attr != 0 && oe == hipSuccess && nb >= 1 &&
                 (long)nb * ncu >= 512) ? 1 : 0;
    }

    if (coop_ok) {
      void* kargs[4] = {(void*)&inputs, (void*)&query, (void*)&kbf, (void*)&out};
      hipError_t e = hipLaunchCooperativeKernel((const void*)attn_coop,
                                                dim3(512), dim3(512), kargs,
                                                0, stream);
      if (e == hipSuccess) return;
      coop_ok = 0;  // fall through to non-coop path
    }

    conv_k    <<<dim3(1024), dim3(512), 0, stream>>>(inputs, kbf);
    attn_fused<<<dim3(1024), dim3(512), 0, stream>>>(kbf, query, out);
  } else {
    float* c_ws = (float*)d_ws;                 // 1 MB
    attn_qk<<<dim3(512), dim3(512), 0, stream>>>(inputs, query, c_ws);
    attn_av<4><<<dim3(1024), dim3(256), 0, stream>>>(inputs, c_ws, out);
  }
}

// Round 6
// 196.395 us; speedup vs baseline: 1.1400x; 1.0234x over previous
//
#include <hip/hip_runtime.h>
#include <hip/hip_bf16.h>

// DotAttention pooled: out[b,d] = sum_t c[b,t]*V[b,t,d],
//   c[b,t] = sum_q exp(s[q,t])/l_q (no-max softmax: s~N(0,1), exp safe),
//   s = (Q K^T)/16,  V == K == inputs.
//
// V7 path (needs 32 MB workspace):
//   conv_k     : inputs fp32 -> bf16, pre-swizzled 32-row tiles (as before).
//   attn_fused : per (b, 64-q block):
//     QK^T over 8 PAIR-intervals (2x 32-row tiles each): 16 ds_read +
//     16 MFMA per barrier interval (was 8+8 over 16 intervals — the
//     per-interval sync stall, ~2 us each, dominated QK; halving the
//     interval count is the lever). 2-pair ring (4 x 16 KB slots);
//     next pair staged at the END of the body, after the MFMAs that
//     consume the slot being overwritten (full-interval prefetch gap).
//     Counted s_waitcnt vmcnt(4)/(0 last) + raw s_barrier.
//     softmax -> cfin via LDS atomicAdd; AV direct-global (L2-resident).
// REG DISCIPLINE: (512,4) = 128-reg cap, proven no-spill (VGPR 60 + AGPR).
//   (512,6) spilled 76 MB (R4). Coop launch: no gain + unprofilable (R5).
// Fallback path (small ws): previous verified kernels.

typedef __bf16 bf16x8 __attribute__((ext_vector_type(8)));
typedef float  f32x4  __attribute__((ext_vector_type(4)));
typedef unsigned int u32;

#define B_    128
#define Tn    512
#define Dn    256
#define SCALE 0.0625f  // 1/sqrt(256)

#define WAITV4 asm volatile("s_waitcnt vmcnt(4)" ::: "memory")
#define WAITV0 asm volatile("s_waitcnt vmcnt(0)" ::: "memory")
#define BARRAW __builtin_amdgcn_s_barrier()
#define SCHED0 __builtin_amdgcn_sched_barrier(0)

// LDS index (bf16 units) for (row, 16B chunk); full xor swizzle — measured
// 0 bank conflicts. Valid for row in [0,32) tiles (row&31 == row).
__device__ __forceinline__ int lidx(int row, int ch) {
  return row * 256 + (((ch ^ (row & 31)) & 31) << 3);
}

__device__ __forceinline__ bf16x8 pack8(float4 v0, float4 v1) {
  bf16x8 w;
  w[0] = (__bf16)v0.x; w[1] = (__bf16)v0.y;
  w[2] = (__bf16)v0.z; w[3] = (__bf16)v0.w;
  w[4] = (__bf16)v1.x; w[5] = (__bf16)v1.y;
  w[6] = (__bf16)v1.z; w[7] = (__bf16)v1.w;
  return w;
}

// Direct global->LDS 16B copy (dest = wave-uniform base + lane*16).
__device__ __forceinline__ void gll16(const __bf16* g, __bf16* l) {
  __builtin_amdgcn_global_load_lds((const u32 __attribute__((address_space(1)))*)g,
                                   (u32 __attribute__((address_space(3)))*)l,
                                   16, 0, 0);
}

// ---------------- pre-pass: K fp32 -> bf16, tile-swizzled ----------------
// kbf[(b*8+tile64)*16384 + c*8] (c = row*32 + p) holds K[b][tile64*64+row]
// logical chunk ch = p ^ (row&31).  32-row tile t is the contiguous 16 KB
// slice at kbf + b*131072 + t*8192 (row&31 is tile-local for both halves).
__global__ void __launch_bounds__(512) conv_k(const float* __restrict__ inputs,
                                              __bf16* __restrict__ kbf) {
  const int tid = threadIdx.x;
  const int b = blockIdx.x & 127, tile = blockIdx.x >> 7;
#pragma unroll
  for (int i = 0; i < 4; ++i) {
    int c = i * 512 + tid;
    int row = c >> 5, p = c & 31;
    int ch = p ^ (row & 31);
    const float4* s =
        (const float4*)(inputs + ((size_t)b * Tn + tile * 64 + row) * Dn + ch * 8);
    *(bf16x8*)(kbf + (size_t)(b * 8 + tile) * 16384 + (size_t)c * 8) =
        pack8(s[0], s[1]);
  }
}

// ---------------- V7 fused: pair-interval QK^T + softmax + direct-AV ----------------
__global__ void __launch_bounds__(512, 4) attn_fused(
    const __bf16* __restrict__ kbf, const float* __restrict__ query,
    float* __restrict__ out) {
  // Ring: 4 x 16 KB tile slots (2 pair-buffers). Scratch: lred 128 f32 |
  // cfin 512 f32. Total 68096 B -> 2 blocks/CU (136 KB < 160 KB).
  __shared__ __bf16 smem[4 * 8192 + 1280];
  float* lred = (float*)(smem + 4 * 8192);  // [qg][th][16 q]
  float* cfin = lred + 128;                 // [512 t], atomic accum

  const int tid  = threadIdx.x;
  const int b  = blockIdx.x & 127;  // same-b blocks 128 apart -> same XCD
  const int qt = blockIdx.x >> 7;   // 0..7 (64 q each)

  const int wave = tid >> 6, lane = tid & 63;
  const int quad = lane >> 4, l15 = lane & 15;
  const int qg = wave >> 1;  // 0..3: 16 q rows each
  const int th = wave & 1;   // 16-row half of each 32-row tile

  const __bf16* ksrc = kbf + (size_t)b * 131072;  // 8192 bf16 / 32-row tile

  cfin[tid] = 0.f;  // ordered vs use by the QK-loop barriers

  // Stage 32-row tile t (16 KB; wave w copies slices 2w, 2w+1) into ring
  // slot (t&3).
#define STAGE(t)                                                        \
  {                                                                     \
    _Pragma("unroll") for (int i_ = 0; i_ < 2; ++i_) {                  \
      int s_ = wave * 2 + i_;                                           \
      gll16(ksrc + (size_t)(t) * 8192 + s_ * 512 + lane * 8,            \
            smem + ((t) & 3) * 8192 + s_ * 512);                        \
    }                                                                   \
  }

  // Prologue: pair0 (tiles 0,1), Q->reg loads, pair1 (tiles 2,3).
  STAGE(0); STAGE(1);

  const float* qsrc = query + ((size_t)b * 512 + qt * 64 + qg * 16 + l15) * Dn;
  bf16x8 a_[8];  // 32 VGPR
#pragma unroll
  for (int dc = 0; dc < 8; ++dc) {
    const float4* p = (const float4*)(qsrc + dc * 32 + quad * 8);
    a_[dc] = pack8(p[0], p[1]);
  }

  STAGE(2); STAGE(3);

  // acc[ti]: S[q = qt*64+qg*16+quad*4+r][t = ti*32 + th*16 + l15]
  f32x4 acc[16];
  f32x4 zero = {0.f, 0.f, 0.f, 0.f};
#pragma unroll
  for (int i = 0; i < 16; ++i) acc[i] = zero;

  // ---- QK^T loop: 8 pair-intervals -------------------------------------
  // Entering p: outstanding = pair p (4 loads) + pair p+1 (4) [+ a_ 8 at
  // p=0, older than pair1]. vmcnt(4) retires pair p (and a_ at p=0);
  // barrier publishes all waves' pair-p LDS writes; compute 16 MFMA;
  // then stage pair p+2 into pair-p's slots — its reads were all consumed
  // by this body's MFMAs (compiler's lgkm waits), SCHED0 pins the order.
  // Prefetch gap = one full interval >> L2 latency.
#pragma unroll
  for (int p = 0; p < 8; ++p) {
    if (p < 7) { WAITV4; } else { WAITV0; }
    BARRAW;
    SCHED0;
    const __bf16* cur0 = smem + ((2 * p) & 3) * 8192;
    const __bf16* cur1 = smem + ((2 * p + 1) & 3) * 8192;
    __builtin_amdgcn_s_setprio(1);
#pragma unroll
    for (int dc = 0; dc < 8; ++dc) {
      bf16x8 b0 = *(const bf16x8*)(cur0 + lidx(th * 16 + l15, dc * 4 + quad));
      bf16x8 b1 = *(const bf16x8*)(cur1 + lidx(th * 16 + l15, dc * 4 + quad));
      acc[2 * p] = __builtin_amdgcn_mfma_f32_16x16x32_bf16(
          a_[dc], b0, acc[2 * p], 0, 0, 0);
      acc[2 * p + 1] = __builtin_amdgcn_mfma_f32_16x16x32_bf16(
          a_[dc], b1, acc[2 * p + 1], 0, 0, 0);
    }
    __builtin_amdgcn_s_setprio(0);
    SCHED0;
    if (p < 6) { STAGE(2 * p + 4); STAGE(2 * p + 5); }
  }

  // ---- softmax epilogue: exp, l_q, column weights into cfin ----
  float rs[4] = {0.f, 0.f, 0.f, 0.f};
#pragma unroll
  for (int ti = 0; ti < 16; ++ti)
#pragma unroll
    for (int r = 0; r < 4; ++r) {
      float pv = __expf(acc[ti][r] * SCALE);
      acc[ti][r] = pv;
      rs[r] += pv;
    }
#pragma unroll
  for (int off = 1; off <= 8; off <<= 1)
#pragma unroll
    for (int r = 0; r < 4; ++r) rs[r] += __shfl_xor(rs[r], off);

  if (l15 == 0) {
#pragma unroll
    for (int r = 0; r < 4; ++r)
      lred[(qg * 2 + th) * 16 + quad * 4 + r] = rs[r];
  }
  __syncthreads();

  float linv[4];
#pragma unroll
  for (int r = 0; r < 4; ++r) {
    int row = quad * 4 + r;
    linv[r] =
        1.f / (lred[(qg * 2 + 0) * 16 + row] + lred[(qg * 2 + 1) * 16 + row]);
  }

#pragma unroll
  for (int ti = 0; ti < 16; ++ti) {
    float v = 0.f;
#pragma unroll
    for (int r = 0; r < 4; ++r) v += acc[ti][r] * linv[r];
    v += __shfl_xor(v, 16);  // sum 4 quads (same t, different q rows)
    v += __shfl_xor(v, 32);
    if (quad == 0) atomicAdd(&cfin[ti * 32 + th * 16 + l15], v);
  }
  __syncthreads();

  // ---- AV pass: V rows direct from global (L2-resident kbf slice) ----
  const int dchunk = tid & 31;
  const int tgrp   = tid >> 5;
  float o[8] = {0.f, 0.f, 0.f, 0.f, 0.f, 0.f, 0.f, 0.f};

#pragma unroll 8
  for (int i = 0; i < 32; ++i) {
    int row = tgrp + i * 16;
    int pp = (dchunk ^ (row & 31)) & 31;
    const bf16x8* src = (const bf16x8*)(ksrc + (size_t)(row >> 6) * 16384 +
                                        ((row & 63) * 32 + pp) * 8);
    bf16x8 v = *src;
    float c = cfin[row];  // lanes 0-31 same row -> LDS broadcast
#pragma unroll
    for (int j = 0; j < 8; ++j) o[j] += c * (float)v[j];
  }
  __syncthreads();  // about to overlay ring with ored

  float* ored = (float*)smem;
  f32x4 o0 = {o[0], o[1], o[2], o[3]}, o1 = {o[4], o[5], o[6], o[7]};
  *(f32x4*)&ored[tgrp * 260 + dchunk * 8]     = o0;
  *(f32x4*)&ored[tgrp * 260 + dchunk * 8 + 4] = o1;
  __syncthreads();
  if (tid < 256) {
    float s = 0.f;
#pragma unroll
    for (int g = 0; g < 16; ++g) s += ored[g * 260 + tid];
    atomicAdd(out + (size_t)b * 256 + tid, s);
  }
#undef STAGE
}

// ---------------- legacy small-ws fallback ----------------
__device__ __forceinline__ void kload(const float* __restrict__ src, int tid,
                                      float4* pre) {
#pragma unroll
  for (int i = 0; i < 4; ++i) {
    int u = i * 512 + tid;
    int row = u >> 5, ch = u & 31;
    const float4* p = (const float4*)(src + row * 256 + ch * 8);
    pre[2 * i]     = p[0];
    pre[2 * i + 1] = p[1];
  }
}

__device__ __forceinline__ void kstore(__bf16* dst, int tid,
                                       const float4* pre) {
#pragma unroll
  for (int i = 0; i < 4; ++i) {
    int u = i * 512 + tid;
    int row = u >> 5, ch = u & 31;
    *(bf16x8*)(dst + lidx(row, ch)) = pack8(pre[2 * i], pre[2 * i + 1]);
  }
}

__global__ void __launch_bounds__(512, 2) attn_qk(
    const float* __restrict__ inputs, const float* __restrict__ query,
    float* __restrict__ c_ws) {
  __shared__ __bf16 smem[128 * 256 + 2 * 64 * 256];
  __bf16* Qs = smem;
  __bf16* Kb[2] = {smem + 128 * 256, smem + 128 * 256 + 64 * 256};

  const int tid  = threadIdx.x;
  const int b  = blockIdx.x & 127;
  const int qt = blockIdx.x >> 7;

  const float* qsrc = query  + ((size_t)b * 512 + (size_t)qt * 128) * Dn;
  const float* ksrc = inputs + (size_t)b * Tn * Dn;

  const int wave = tid >> 6, lane = tid & 63;
  const int quad = lane >> 4, l15 = lane & 15;
  const int qg = wave >> 1;
  const int th = wave & 1;

  float4 pre[2][8];
  kload(ksrc, tid, pre[0]);

#pragma unroll
  for (int i = 0; i < 8; ++i) {
    int u = i * 512 + tid;
    int row = u >> 5, ch = u & 31;
    const float4* p = (const float4*)(qsrc + row * 256 + ch * 8);
    *(bf16x8*)(Qs + lidx(row, ch)) = pack8(p[0], p[1]);
  }

  kload(ksrc + (size_t)1 * 64 * Dn, tid, pre[1]);
  __syncthreads();

  kstore(Kb[0], tid, pre[0]);
  kload(ksrc + (size_t)2 * 64 * Dn, tid, pre[0]);
  __syncthreads();

  f32x4 acc[8][2][2];
  f32x4 zero = {0.f, 0.f, 0.f, 0.f};
#pragma unroll
  for (int tt = 0; tt < 8; ++tt)
#pragma unroll
    for (int ct = 0; ct < 2; ++ct) {
      acc[tt][ct][0] = zero;
      acc[tt][ct][1] = zero;
    }

#pragma unroll
  for (int tt = 0; tt < 8; ++tt) {
    if (tt < 7) kstore(Kb[(tt + 1) & 1], tid, pre[(tt + 1) & 1]);
    if (tt < 5) kload(ksrc + (size_t)(tt + 3) * 64 * Dn, tid, pre[(tt + 1) & 1]);

    const __bf16* cur = Kb[tt & 1];
#pragma unroll
    for (int dc = 0; dc < 8; ++dc) {
      bf16x8 a0 = *(const bf16x8*)(Qs + lidx(qg * 32 + l15, dc * 4 + quad));
      bf16x8 a1 = *(const bf16x8*)(Qs + lidx(qg * 32 + 16 + l15, dc * 4 + quad));
#pragma unroll
      for (int ct = 0; ct < 2; ++ct) {
        bf16x8 bb =
            *(const bf16x8*)(cur + lidx(th * 32 + ct * 16 + l15, dc * 4 + quad));
        acc[tt][ct][0] = __builtin_amdgcn_mfma_f32_16x16x32_bf16(
            a0, bb, acc[tt][ct][0], 0, 0, 0);
        acc[tt][ct][1] = __builtin_amdgcn_mfma_f32_16x16x32_bf16(
            a1, bb, acc[tt][ct][1], 0, 0, 0);
      }
    }
    __syncthreads();
  }

  float* lred  = (float*)Kb[0];
  float* cpart = (float*)Kb[0] + 256;

  float rs[2][4];
#pragma unroll
  for (int m = 0; m < 2; ++m)
#pragma unroll
    for (int r = 0; r < 4; ++r) rs[m][r] = 0.f;
#pragma unroll
  for (int tt = 0; tt < 8; ++tt)
#pragma unroll
    for (int ct = 0; ct < 2; ++ct)
#pragma unroll
      for (int m = 0; m < 2; ++m)
#pragma unroll
        for (int r = 0; r < 4; ++r) {
          float p = __expf(acc[tt][ct][m][r] * SCALE);
          acc[tt][ct][m][r] = p;
          rs[m][r] += p;
        }
#pragma unroll
  for (int off = 1; off <= 8; off <<= 1)
#pragma unroll
    for (int m = 0; m < 2; ++m)
#pragma unroll
      for (int r = 0; r < 4; ++r) rs[m][r] += __shfl_xor(rs[m][r], off);

  if (l15 == 0) {
#pragma unroll
    for (int m = 0; m < 2; ++m)
#pragma unroll
      for (int r = 0; r < 4; ++r)
        lred[(qg * 2 + th) * 32 + m * 16 + quad * 4 + r] = rs[m][r];
  }
  __syncthreads();

  float linv[2][4];
#pragma unroll
  for (int m = 0; m < 2; ++m)
#pragma unroll
    for (int r = 0; r < 4; ++r) {
      int row = m * 16 + quad * 4 + r;
      linv[m][r] =
          1.f / (lred[(qg * 2 + 0) * 32 + row] + lred[(qg * 2 + 1) * 32 + row]);
    }

#pragma unroll
  for (int tt = 0; tt < 8; ++tt)
#pragma unroll
    for (int ct = 0; ct < 2; ++ct) {
      float v = 0.f;
#pragma unroll
      for (int m = 0; m < 2; ++m)
#pragma unroll
        for (int r = 0; r < 4; ++r) v += acc[tt][ct][m][r] * linv[m][r];
      v += __shfl_xor(v, 16);
      v += __shfl_xor(v, 32);
      if (quad == 0)
        cpart[qg * 512 + tt * 64 + th * 32 + ct * 16 + l15] = v;
    }
  __syncthreads();

  float* cout = c_ws + ((size_t)qt * B_ + b) * Tn;
#pragma unroll
  for (int t = tid; t < 512; t += 256) {
    if (t < 512)
      cout[t] = cpart[t] + cpart[512 + t] + cpart[1024 + t] + cpart[1536 + t];
  }
}

template <int NSL>
__global__ void __launch_bounds__(256) attn_av(
    const float* __restrict__ inputs, const float* __restrict__ c_ws,
    float* __restrict__ out) {
  __shared__ float cs[64];
  __shared__ float psum[3][256];
  const int bid = blockIdx.x, tid = threadIdx.x;
  const int b = bid & 127, sl = bid >> 7;

  if (tid < 64) {
    int t = sl * 64 + tid;
    float s = 0.f;
#pragma unroll
    for (int i = 0; i < NSL; ++i) s += c_ws[(size_t)(i * B_ + b) * Tn + t];
    cs[tid] = s;
  }
  __syncthreads();

  const int w = tid >> 6, d4 = tid & 63;
  const float4* vb =
      (const float4*)(inputs + ((size_t)b * Tn + sl * 64 + w * 16) * Dn) + d4;
  float ox = 0.f, oy = 0.f, oz = 0.f, ow = 0.f;
#pragma unroll
  for (int j = 0; j < 16; ++j) {
    float c = cs[w * 16 + j];
    float4 v = vb[(size_t)j * 64];
    ox += c * v.x; oy += c * v.y; oz += c * v.z; ow += c * v.w;
  }
  if (w) {
    float4 t = {ox, oy, oz, ow};
    *(float4*)&psum[w - 1][d4 * 4] = t;
  }
  __syncthreads();
  if (!w) {
    float4 p0 = *(float4*)&psum[0][d4 * 4];
    float4 p1 = *(float4*)&psum[1][d4 * 4];
    float4 p2 = *(float4*)&psum[2][d4 * 4];
    float* op = out + b * 256 + d4 * 4;
    atomicAdd(op + 0, ox + p0.x + p1.x + p2.x);
    atomicAdd(op + 1, oy + p0.y + p1.y + p2.y);
    atomicAdd(op + 2, oz + p0.z + p1.z + p2.z);
    atomicAdd(op + 3, ow + p0.w + p1.w + p2.w);
  }
}

extern "C" void kernel_launch(void* const* d_in, const int* in_sizes, int n_in,
                              void* d_out, int out_size, void* d_ws, size_t ws_size,
                              hipStream_t stream) {
  const float* inputs = (const float*)d_in[0];  // [B,T,D]
  const float* query  = (const float*)d_in[1];  // [B,Q,D]
  float* out  = (float*)d_out;                  // [B,D]

  hipMemsetAsync(out, 0, (size_t)B_ * Dn * sizeof(float), stream);

  const size_t kbytes = (size_t)B_ * Tn * Dn * sizeof(__bf16);  // 32 MB
  if (ws_size >= kbytes) {
    __bf16* kbf = (__bf16*)d_ws;
    conv_k    <<<dim3(1024), dim3(512), 0, stream>>>(inputs, kbf);
    attn_fused<<<dim3(1024), dim3(512), 0, stream>>>(kbf, query, out);
  } else {
    float* c_ws = (float*)d_ws;                 // 1 MB
    attn_qk<<<dim3(512), dim3(512), 0, stream>>>(inputs, query, c_ws);
    attn_av<4><<<dim3(1024), dim3(256), 0, stream>>>(inputs, c_ws, out);
  }
}